// Round 1
// 523.022 us; speedup vs baseline: 1.0649x; 1.0649x over previous
//
#include <hip/hip_runtime.h>

#define NTOK 64
#define DIM 192
#define HEADS 6
#define HD 32
#define SCALE 0.17677669529663687f  // 32^-0.5
#define XSS 200                     // xs row stride in ushorts (400 B, 16B-aligned)

typedef __bf16 bf16x8 __attribute__((ext_vector_type(8)));
typedef float f32x4 __attribute__((ext_vector_type(4)));

union U8 { bf16x8 v; unsigned short s[8]; };
union F4 { float4 v; float f[4]; };

__device__ __forceinline__ unsigned short f2bf(float f) {
  union { float f; unsigned u; } v; v.f = f;
  unsigned u = v.u;
  return (unsigned short)((u + 0x7FFFu + ((u >> 16) & 1u)) >> 16);
}

// ---------------- pre-pass: weights -> bf16, bias gather -> dense ----------
__global__ void prep_kernel(const float* __restrict__ qkv_w,
                            const float* __restrict__ proj_w,
                            const float* __restrict__ bias_table,
                            const int* __restrict__ rel_idx,
                            unsigned short* __restrict__ wq,
                            unsigned short* __restrict__ wp,
                            float* __restrict__ biasf) {
  int i = blockIdx.x * 256 + threadIdx.x;
  if (i < 3 * DIM * DIM) wq[i] = f2bf(qkv_w[i]);
  if (i < DIM * DIM) wp[i] = f2bf(proj_w[i]);
  if (i < HEADS * NTOK * NTOK) {
    int h = i >> 12;       // 4096 entries per head
    int nm = i & 4095;
    biasf[i] = bias_table[rel_idx[nm] * HEADS + h];
  }
}

// ---------------- fused window attention: 1 block = 1 window ----------------
// Register-resident pipeline. The only LDS is the x staging buffer (25.6 KB),
// reused for the attention-output -> proj handoff. q/k/v/P never touch LDS:
// permuted-row operand loads make every GEMM output land directly in the
// register layout the next MFMA consumes.
//   pi_dt(i) = (i>>2)*8 + 4*dt + (i&3)   (A-row permutation)
__global__ __launch_bounds__(384) void attn_kernel(
    const float* __restrict__ x,
    const float* __restrict__ qkv_b,
    const float* __restrict__ proj_b,
    const unsigned short* __restrict__ wq,
    const unsigned short* __restrict__ wp,
    const float* __restrict__ biasf,
    float* __restrict__ out) {
  __shared__ unsigned short xs[NTOK * XSS];  // 25600 B

  const int tid = threadIdx.x;
  const int w = tid >> 6;       // wave 0..5 == head
  const int lane = tid & 63;
  const int l15 = lane & 15;
  const int quad = lane >> 4;
  const long b = blockIdx.x;
  const int h = w;

  // ---- stage 1: load x (fp32) -> LDS bf16 ----
  {
    const float4* xg = (const float4*)(x + b * (NTOK * DIM));
    #pragma unroll
    for (int it = 0; it < 8; ++it) {
      int idx = tid + it * 384;        // 3072 float4 total
      float4 v = xg[idx];
      int row = idx / 48;
      int col = (idx % 48) * 4;
      ushort4 o;
      o.x = f2bf(v.x); o.y = f2bf(v.y); o.z = f2bf(v.z); o.w = f2bf(v.w);
      *(ushort4*)&xs[row * XSS + col] = o;
    }
  }
  __syncthreads();

  const int prm = ((l15 >> 2) << 3) | (l15 & 3);  // pi_0(l15), pi_1 = prm+4
  const f32x4 zero = {0.f, 0.f, 0.f, 0.f};

  // ---- step A: transposed q GEMM -> qfrag[nt] (lane: q[n=16nt+l15][d=8q+jj])
  bf16x8 qfrag[4];
  {
    const unsigned short* wqh = wq + ((size_t)h * 32) * DIM;
    F4 qb0, qb1;
    qb0.v = *(const float4*)(qkv_b + h * 32 + quad * 8);
    qb1.v = *(const float4*)(qkv_b + h * 32 + quad * 8 + 4);
    #pragma unroll
    for (int nt = 0; nt < 4; ++nt) {
      bf16x8 xn[6];
      #pragma unroll
      for (int ks = 0; ks < 6; ++ks)
        xn[ks] = *(const bf16x8*)&xs[(nt * 16 + l15) * XSS + ks * 32 + quad * 8];
      f32x4 a0 = zero, a1 = zero;
      #pragma unroll
      for (int ks = 0; ks < 6; ++ks) {
        bf16x8 w0 = *(const bf16x8*)(wqh + (size_t)(prm + 0) * DIM + ks * 32 + quad * 8);
        bf16x8 w1 = *(const bf16x8*)(wqh + (size_t)(prm + 4) * DIM + ks * 32 + quad * 8);
        a0 = __builtin_amdgcn_mfma_f32_16x16x32_bf16(w0, xn[ks], a0, 0, 0, 0);
        a1 = __builtin_amdgcn_mfma_f32_16x16x32_bf16(w1, xn[ks], a1, 0, 0, 0);
      }
      U8 t;
      #pragma unroll
      for (int g = 0; g < 4; ++g) {
        t.s[g]     = f2bf((a0[g] + qb0.f[g]) * SCALE);
        t.s[4 + g] = f2bf((a1[g] + qb1.f[g]) * SCALE);
      }
      qfrag[nt] = t.v;
    }
  }

  // ---- steps B+C: transposed k GEMM (permuted m rows) + v GEMM ----
  // kfrag[mt]: lane holds k[m=Rm_mt(l15)][d=8q+jj], Rm_mt(l)=32kv+4half+pi_0(l)
  // vbu[c2][kv]: lane holds v[m=32kv+8q+jj][d=16c2+l15]
  bf16x8 kfrag[4];
  U8 vbu[2][2];
  {
    const unsigned short* wkh = wq + ((size_t)(192 + h * 32)) * DIM;
    const unsigned short* wvh = wq + ((size_t)(384 + h * 32)) * DIM;
    F4 kb0, kb1;
    kb0.v = *(const float4*)(qkv_b + 192 + h * 32 + quad * 8);
    kb1.v = *(const float4*)(qkv_b + 192 + h * 32 + quad * 8 + 4);
    const float vbias0 = qkv_b[384 + h * 32 + l15];
    const float vbias1 = qkv_b[384 + h * 32 + 16 + l15];
    #pragma unroll
    for (int mt = 0; mt < 4; ++mt) {
      const int kv = mt >> 1, half = mt & 1;
      const int xrow = kv * 32 + half * 4 + prm;   // Rm_mt(l15)
      bf16x8 xp[6];
      #pragma unroll
      for (int ks = 0; ks < 6; ++ks)
        xp[ks] = *(const bf16x8*)&xs[xrow * XSS + ks * 32 + quad * 8];
      f32x4 ka0 = zero, ka1 = zero, va0 = zero, va1 = zero;
      #pragma unroll
      for (int ks = 0; ks < 6; ++ks) {
        bf16x8 wk0 = *(const bf16x8*)(wkh + (size_t)(prm + 0) * DIM + ks * 32 + quad * 8);
        bf16x8 wk1 = *(const bf16x8*)(wkh + (size_t)(prm + 4) * DIM + ks * 32 + quad * 8);
        bf16x8 wv0 = *(const bf16x8*)(wvh + (size_t)(l15 + 0) * DIM + ks * 32 + quad * 8);
        bf16x8 wv1 = *(const bf16x8*)(wvh + (size_t)(l15 + 16) * DIM + ks * 32 + quad * 8);
        ka0 = __builtin_amdgcn_mfma_f32_16x16x32_bf16(wk0, xp[ks], ka0, 0, 0, 0);
        ka1 = __builtin_amdgcn_mfma_f32_16x16x32_bf16(wk1, xp[ks], ka1, 0, 0, 0);
        va0 = __builtin_amdgcn_mfma_f32_16x16x32_bf16(xp[ks], wv0, va0, 0, 0, 0);
        va1 = __builtin_amdgcn_mfma_f32_16x16x32_bf16(xp[ks], wv1, va1, 0, 0, 0);
      }
      U8 t;
      #pragma unroll
      for (int g = 0; g < 4; ++g) {
        t.s[g]     = f2bf(ka0[g] + kb0.f[g]);
        t.s[4 + g] = f2bf(ka1[g] + kb1.f[g]);
        vbu[0][kv].s[half * 4 + g] = f2bf(va0[g] + vbias0);
        vbu[1][kv].s[half * 4 + g] = f2bf(va1[g] + vbias1);
      }
      kfrag[mt] = t.v;
    }
  }

  // ---- stage 3: swapped S GEMM (S^T), softmax, PV — all in registers ----
  // s[mt][nt][g] = S[n=16nt+l15][m = 32kv + 8q + 4half + g]
  f32x4 s[4][4];
  #pragma unroll
  for (int mt = 0; mt < 4; ++mt)
    #pragma unroll
    for (int nt = 0; nt < 4; ++nt)
      s[mt][nt] = __builtin_amdgcn_mfma_f32_16x16x32_bf16(kfrag[mt], qfrag[nt], zero, 0, 0, 0);

  bf16x8 pa[4][2];   // lane: P[n=16nt+l15][m=32kv+8q+jj]
  {
    const float* bh = biasf + h * 4096;
    #pragma unroll
    for (int nt = 0; nt < 4; ++nt) {
      float ve[16];
      #pragma unroll
      for (int mt = 0; mt < 4; ++mt) {
        F4 bb;
        bb.v = *(const float4*)(bh + (nt * 16 + l15) * 64 + (mt >> 1) * 32 + quad * 8 + (mt & 1) * 4);
        #pragma unroll
        for (int g = 0; g < 4; ++g) ve[mt * 4 + g] = s[mt][nt][g] + bb.f[g];
      }
      float mx = ve[0];
      #pragma unroll
      for (int t = 1; t < 16; ++t) mx = fmaxf(mx, ve[t]);
      mx = fmaxf(mx, __shfl_xor(mx, 16));
      mx = fmaxf(mx, __shfl_xor(mx, 32));
      float sm = 0.f;
      #pragma unroll
      for (int t = 0; t < 16; ++t) { ve[t] = __expf(ve[t] - mx); sm += ve[t]; }
      sm += __shfl_xor(sm, 16);
      sm += __shfl_xor(sm, 32);
      float r = __builtin_amdgcn_rcpf(sm);
      U8 t0, t1;
      #pragma unroll
      for (int j = 0; j < 8; ++j) {
        t0.s[j] = f2bf(ve[j] * r);
        t1.s[j] = f2bf(ve[8 + j] * r);
      }
      pa[nt][0] = t0.v;
      pa[nt][1] = t1.v;
    }
  }

  f32x4 o[4][2];
  #pragma unroll
  for (int nt = 0; nt < 4; ++nt)
    #pragma unroll
    for (int c2 = 0; c2 < 2; ++c2) {
      f32x4 acc = __builtin_amdgcn_mfma_f32_16x16x32_bf16(pa[nt][0], vbu[c2][0].v, zero, 0, 0, 0);
      o[nt][c2] = __builtin_amdgcn_mfma_f32_16x16x32_bf16(pa[nt][1], vbu[c2][1].v, acc, 0, 0, 0);
    }

  // wait until every wave is done reading xs, then overwrite it with attn-out
  __syncthreads();
  #pragma unroll
  for (int nt = 0; nt < 4; ++nt)
    #pragma unroll
    for (int c2 = 0; c2 < 2; ++c2)
      #pragma unroll
      for (int g = 0; g < 4; ++g)
        xs[(nt * 16 + quad * 4 + g) * XSS + h * 32 + c2 * 16 + l15] = f2bf(o[nt][c2][g]);
  __syncthreads();

  // ---- stage 4: proj GEMM  out[n][e] = sum_f a[n][f] Wp[e][f] + pb[e] ----
  {
    bf16x8 af[4][6];
    #pragma unroll
    for (int nt = 0; nt < 4; ++nt)
      #pragma unroll
      for (int ks = 0; ks < 6; ++ks)
        af[nt][ks] = *(const bf16x8*)&xs[(nt * 16 + l15) * XSS + ks * 32 + quad * 8];
    float* og = out + b * (NTOK * DIM);
    #pragma unroll
    for (int i = 0; i < 2; ++i) {
      const int e = w * 32 + i * 16 + l15;
      f32x4 acc[4] = {zero, zero, zero, zero};
      #pragma unroll
      for (int ks = 0; ks < 6; ++ks) {
        bf16x8 bw = *(const bf16x8*)(wp + (size_t)e * DIM + ks * 32 + quad * 8);
        #pragma unroll
        for (int nt = 0; nt < 4; ++nt)
          acc[nt] = __builtin_amdgcn_mfma_f32_16x16x32_bf16(af[nt][ks], bw, acc[nt], 0, 0, 0);
      }
      const float pb = proj_b[e];
      #pragma unroll
      for (int nt = 0; nt < 4; ++nt)
        #pragma unroll
        for (int g = 0; g < 4; ++g)
          og[(nt * 16 + quad * 4 + g) * DIM + e] = acc[nt][g] + pb;
    }
  }
}

extern "C" void kernel_launch(void* const* d_in, const int* in_sizes, int n_in,
                              void* d_out, int out_size, void* d_ws, size_t ws_size,
                              hipStream_t stream) {
  const float* x          = (const float*)d_in[0];
  const float* qkv_w      = (const float*)d_in[1];
  const float* qkv_b      = (const float*)d_in[2];
  const float* proj_w     = (const float*)d_in[3];
  const float* proj_b     = (const float*)d_in[4];
  const float* bias_table = (const float*)d_in[5];
  const int*   rel_idx    = (const int*)d_in[6];

  unsigned short* wq = (unsigned short*)d_ws;            // 110592 bf16
  unsigned short* wp = wq + 3 * DIM * DIM;               // 36864 bf16
  float* biasf = (float*)(wp + DIM * DIM);               // 24576 fp32

  prep_kernel<<<432, 256, 0, stream>>>(qkv_w, proj_w, bias_table, rel_idx, wq, wp, biasf);
  attn_kernel<<<4096, 384, 0, stream>>>(x, qkv_b, proj_b, wq, wp, biasf, (float*)d_out);
}